// Round 9
// baseline (253.941 us; speedup 1.0000x reference)
//
#include <hip/hip_runtime.h>

// Fused MHA: qkv[4,2048,1024] f32 -> out f32, all GEMMs in bf16 MFMA.
// R15: flash v8 — occupancy restructure. v7 counters: MfmaUtil 35, VALU 42,
// HBM 6%, Occupancy 18.8% (=6 waves/CU) -> latency-bound, pipes undermixed.
// QBLK 256->128, KVBLK 128->64: grid 1024 blocks, LDS 40KB (sK 2x8K +
// sV 2x8K + sP 4x2K) -> 4 blocks/CU (163840B exactly), 16 waves/CU; per-wave
// tiles halve (ctxa 32 VGPR, 2x K-step kq loop, 32 its). Same total MFMA/
// exp/HBM work; barriers overlap across 4 independent blocks. All swizzles
// re-audited at new sizes (2-way max = free, m136). XCD swizzle: 8 bh/XCD,
// KV 2MB L2-resident. Non-flash time measured invariant (~162us) across 3
// gemm1 structures (R12/R14) -> gemm theories retired; if flash drops below
// gemm1, gemm1 surfaces in top-5 = free visibility next round.
// gemm1 (R14 256x192), gemm2, prep unchanged (controls).

typedef __bf16 bf16;
typedef __bf16 bf16x4 __attribute__((ext_vector_type(4)));
typedef __bf16 bf16x8 __attribute__((ext_vector_type(8)));
typedef float f32x4 __attribute__((ext_vector_type(4)));

typedef const __attribute__((address_space(1))) void* gas1p;
typedef __attribute__((address_space(3))) void* las3p;
#define GLD16(g, l) __builtin_amdgcn_global_load_lds((gas1p)(g), (las3p)(l), 16, 0, 0)

#if __has_builtin(__builtin_amdgcn_exp2f)
#define EXP2(x) __builtin_amdgcn_exp2f(x)
#else
#define EXP2(x) exp2f(x)
#endif

// counted vmcnt wait; memory clobber keeps all VMEM/DS ops on their side.
#define WAITV(n) asm volatile("s_waitcnt vmcnt(" #n ")" ::: "memory")

__device__ __forceinline__ void barp() {
  __builtin_amdgcn_sched_barrier(0);
  __builtin_amdgcn_s_barrier();
  __builtin_amdgcn_sched_barrier(0);
}

__device__ __forceinline__ f32x4 mfma16(bf16x8 a, bf16x8 b, f32x4 c) {
  return __builtin_amdgcn_mfma_f32_16x16x32_bf16(a, b, c, 0, 0, 0);
}

// ---------------- prep: cast qkv -> bf16, transpose+cast W_in, W_out ----------------
__global__ void prep_kernel(const float* __restrict__ qkv, bf16* __restrict__ Xb,
                            const float* __restrict__ W_in, bf16* __restrict__ WtIn,
                            const float* __restrict__ W_out, bf16* __restrict__ WtOut) {
  __shared__ float tile[32][33];
  int blk = blockIdx.x, tid = threadIdx.x;
  if (blk < 8192) {
    int i = (blk * 256 + tid) * 4;
    float4 v = *(const float4*)(qkv + i);
    bf16x4 o;
    o[0] = (bf16)v.x; o[1] = (bf16)v.y; o[2] = (bf16)v.z; o[3] = (bf16)v.w;
    *(bf16x4*)(Xb + i) = o;
    return;
  }
  const float* in; bf16* out; int R, C, c0, r0;
  if (blk < 11264) {
    int t = blk - 8192; in = W_in; out = WtIn; R = 1024; C = 3072;
    c0 = (t % 96) * 32; r0 = (t / 96) * 32;
  } else {
    int t = blk - 11264; in = W_out; out = WtOut; R = 1024; C = 1024;
    c0 = (t % 32) * 32; r0 = (t / 32) * 32;
  }
  int tx = tid & 31, ty = tid >> 5;
#pragma unroll
  for (int i = 0; i < 4; ++i)
    tile[ty + i * 8][tx] = in[(size_t)(r0 + ty + i * 8) * C + c0 + tx];
  __syncthreads();
#pragma unroll
  for (int i = 0; i < 4; ++i)
    out[(size_t)(c0 + ty + i * 8) * R + r0 + tx] = (bf16)tile[tx][ty + i * 8];
}

// ======== staging helpers (wave-uniform LDS base + lane*16: m104-safe) ========
__device__ __forceinline__ void stage_a256(const bf16* __restrict__ src, int kt,
                                           char* dst, int tid) {
#pragma unroll
  for (int i = 0; i < 4; ++i) {
    int chunk = i * 512 + tid;
    int row = chunk >> 3;
    int cs = (chunk & 7) ^ (row & 7);
    GLD16(src + (size_t)row * 1024 + kt + cs * 8, dst + chunk * 16);
  }
}
__device__ __forceinline__ void stage_b192(const bf16* __restrict__ src, int kt,
                                           char* dst, int tid) {
#pragma unroll
  for (int i = 0; i < 3; ++i) {
    int chunk = i * 512 + tid;
    int row = chunk >> 3;
    int cs = (chunk & 7) ^ (row & 7);
    GLD16(src + (size_t)row * 1024 + kt + cs * 8, dst + chunk * 16);
  }
}
__device__ __forceinline__ void stage_mat(const bf16* __restrict__ src, int kt,
                                          char* dst, int tid) {
#pragma unroll
  for (int i = 0; i < 4; ++i) {
    int chunk = i * 256 + tid;
    int row = chunk >> 3;
    int cs = (chunk & 7) ^ (row & 7);
    GLD16(src + (size_t)row * 1024 + kt + cs * 8, dst + chunk * 16);
  }
}
__device__ __forceinline__ void stage_bhalf(const bf16* __restrict__ src, int kt,
                                            char* dst, int tid, int b) {
#pragma unroll
  for (int i = 0; i < 2; ++i) {
    int chunk = (i * 64 + b * 32) * 8 + tid;
    int row = chunk >> 3;
    int cs = (chunk & 7) ^ (row & 7);
    GLD16(src + (size_t)row * 1024 + kt + cs * 8, dst + chunk * 16);
  }
}

// ---------------- GEMM1 (R14): 256x192 tile, 512 thr, tri-buffered B ----------------
__global__ __launch_bounds__(512, 2) void gemm1_kernel(
    const bf16* __restrict__ A, const bf16* __restrict__ Bt, const float* __restrict__ bias,
    bf16* __restrict__ Qo, bf16* __restrict__ Ko, bf16* __restrict__ Vo) {
  __shared__ __align__(16) char sA[2][256 * 64 * 2];   // 64KB
  __shared__ __align__(16) char sB[3][192 * 64 * 2];   // 72KB
  const int tid = threadIdx.x, lane = tid & 63, quad = lane >> 4;
  const int wave = tid >> 6;
  const int wm = (wave >> 2) * 128, wn = (wave & 3) * 48;
  const int id = blockIdx.x, xcd = id & 7, local = id >> 3;
  const int m0 = (xcd * 4 + (local & 3)) * 256, n0 = (local >> 2) * 192;
  const bf16* Ab = A + (size_t)m0 * 1024;
  const bf16* Bb = Bt + (size_t)n0 * 1024;
  f32x4 acc[8][3] = {};

  stage_b192(Bb, 0, sB[0], tid);
  stage_a256(Ab, 0, sA[0], tid);
  stage_b192(Bb, 64, sB[1], tid);

  for (int t = 0; t < 16; ++t) {
    const char* ca = sA[t & 1];
    const char* cb = sB[t % 3];
    if (t < 15) { WAITV(3); } else { WAITV(0); }
    barp();

    bf16x8 af[4][2], b0r[2][2], b1r[2];
#pragma unroll
    for (int mtl = 0; mtl < 4; ++mtl)
#pragma unroll
      for (int ks = 0; ks < 2; ++ks) {
        int ra = wm + mtl * 16 + (lane & 15);
        af[mtl][ks] = *(const bf16x8*)(ca + ra * 128 + ((ks * 4 + quad) ^ (ra & 7)) * 16);
      }
#pragma unroll
    for (int ntl = 0; ntl < 2; ++ntl)
#pragma unroll
      for (int ks = 0; ks < 2; ++ks) {
        int rb = wn + ntl * 16 + (lane & 15);
        b0r[ntl][ks] = *(const bf16x8*)(cb + rb * 128 + ((ks * 4 + quad) ^ (rb & 7)) * 16);
      }
    if (t < 15) stage_a256(Ab, (t + 1) * 64, sA[(t + 1) & 1], tid);
    if (t < 14) stage_b192(Bb, (t + 2) * 64, sB[(t + 2) % 3], tid);
    __builtin_amdgcn_s_setprio(1);
#pragma unroll
    for (int ks = 0; ks < 2; ++ks)
#pragma unroll
      for (int mtl = 0; mtl < 4; ++mtl)
#pragma unroll
        for (int ntl = 0; ntl < 2; ++ntl)
          acc[mtl][ntl] = mfma16(af[mtl][ks], b0r[ntl][ks], acc[mtl][ntl]);
    __builtin_amdgcn_s_setprio(0);

#pragma unroll
    for (int ks = 0; ks < 2; ++ks) {
      int rb = wn + 32 + (lane & 15);
      b1r[ks] = *(const bf16x8*)(cb + rb * 128 + ((ks * 4 + quad) ^ (rb & 7)) * 16);
    }
    __builtin_amdgcn_s_setprio(1);
#pragma unroll
    for (int ks = 0; ks < 2; ++ks)
#pragma unroll
      for (int mtl = 0; mtl < 4; ++mtl)
        acc[mtl][2] = mfma16(af[mtl][ks], b1r[ks], acc[mtl][2]);
    __builtin_amdgcn_s_setprio(0);

#pragma unroll
    for (int mtl = 0; mtl < 4; ++mtl)
#pragma unroll
      for (int ks = 0; ks < 2; ++ks) {
        int ra = wm + 64 + mtl * 16 + (lane & 15);
        af[mtl][ks] = *(const bf16x8*)(ca + ra * 128 + ((ks * 4 + quad) ^ (ra & 7)) * 16);
      }
    __builtin_amdgcn_s_setprio(1);
#pragma unroll
    for (int ks = 0; ks < 2; ++ks)
#pragma unroll
      for (int mtl = 0; mtl < 4; ++mtl)
#pragma unroll
        for (int ntl = 0; ntl < 2; ++ntl)
          acc[4 + mtl][ntl] = mfma16(af[mtl][ks], b0r[ntl][ks], acc[4 + mtl][ntl]);
#pragma unroll
    for (int ks = 0; ks < 2; ++ks)
#pragma unroll
      for (int mtl = 0; mtl < 4; ++mtl)
        acc[4 + mtl][2] = mfma16(af[mtl][ks], b1r[ks], acc[4 + mtl][2]);
    __builtin_amdgcn_s_setprio(0);
  }

#pragma unroll
  for (int ntl = 0; ntl < 3; ++ntl) {
    int n = n0 + wn + ntl * 16 + (lane & 15);
    float bv = bias[n];
    int region = n >> 10;  // 0=Q, 1=K, 2=V
    int ncol = n & 1023;
    int h = ncol >> 6, d = ncol & 63;
    float scl = (region == 0) ? 0.18033688f : 1.0f;  // 1/sqrt(64)*log2(e)
#pragma unroll
    for (int mtl = 0; mtl < 8; ++mtl) {
      int gm = m0 + wm + mtl * 16 + quad * 4;
      int bb = gm >> 11, s = gm & 2047;
      if (region == 2) {
        bf16x4 pk;
#pragma unroll
        for (int r = 0; r < 4; ++r) pk[r] = (bf16)(acc[mtl][ntl][r] + bv);
        *(bf16x4*)(Vo + ((size_t)((bb * 16 + h) * 64 + d)) * 2048 + s) = pk;
      } else {
        bf16* dst = (region == 0) ? Qo : Ko;
#pragma unroll
        for (int r = 0; r < 4; ++r)
          dst[((size_t)((bb * 16 + h) * 2048) + s + r) * 64 + d] =
              (bf16)((acc[mtl][ntl][r] + bv) * scl);
      }
    }
  }
}

// ---------------- flash attention v8: QBLK=128, KVBLK=64, 4 blocks/CU ----------------
__global__ __launch_bounds__(256, 4) void flash_kernel(
    const bf16* __restrict__ Q, const bf16* __restrict__ K, const bf16* __restrict__ Vt,
    bf16* __restrict__ ctx) {
  const int n = blockIdx.x;
  const int bh = (n & 7) * 8 + (n >> 7);   // XCD swizzle: 8 bh share an XCD L2
  const int qt = (n >> 3) & 15;
  const int b = bh >> 4, h = bh & 15;
  const int tid = threadIdx.x, lane = tid & 63, wave = tid >> 6, quad = lane >> 4;

  __shared__ __align__(16) char sK[2][64 * 64 * 2];   // K dbuf, 2x8KB
  __shared__ __align__(16) char sV[2][64 * 64 * 2];   // V dbuf [d][kv], 2x8KB
  __shared__ __align__(16) char sP[4][32 * 32 * 2];   // per-wave [32q][32kv] 2KB

  const size_t hb = (size_t)bh * 2048 * 64;
  const int q0 = qt * 128;

  // ---- Q prologue: 128 rows x 64 d = 16KB staged into sK[0..1] (contiguous)
#pragma unroll
  for (int i = 0; i < 4; ++i) {
    int chunk = i * 256 + tid;
    int row = chunk >> 3;
    int cs = (chunk & 7) ^ (row & 7);
    GLD16(Q + hb + (size_t)(q0 + row) * 64 + cs * 8, sK[0] + chunk * 16);
  }
  __syncthreads();
  bf16x8 qf[2][2];
#pragma unroll
  for (int j = 0; j < 2; ++j)
#pragma unroll
    for (int ksd = 0; ksd < 2; ++ksd) {
      int row = wave * 32 + j * 16 + (lane & 15);
      qf[j][ksd] = *(const bf16x8*)(sK[0] + row * 128 + ((ksd * 4 + quad) ^ (row & 7)) * 16);
    }
  __syncthreads();

  // ---- K/V tile 0: K [64kv][64d] 8KB + V [64d][64kv] 8KB = 4 GLD16/thread
#pragma unroll
  for (int i = 0; i < 4; ++i) {
    int chunk = i * 256 + tid;
    if (chunk < 512) {
      int row = chunk >> 3;
      int cs = (chunk & 7) ^ (row & 7);
      GLD16(K + hb + (size_t)row * 64 + cs * 8, sK[0] + chunk * 16);
    } else {
      int vc = chunk - 512;
      int vrow = vc >> 3;
      int vcs = (vc & 7) ^ (vrow & 7);
      GLD16(Vt + hb + (size_t)vrow * 2048 + vcs * 8, sV[0] + vc * 16);
    }
  }
  __syncthreads();

  f32x4 ctxa[2][4] = {};
  float l[2] = {0.f, 0.f};
  char* pw = sP[wave];

  for (int it = 0; it < 32; ++it) {
    const int kv0 = it * 64;
    if (it < 31) {
      char* nk = sK[(it + 1) & 1];
      char* nv = sV[(it + 1) & 1];
#pragma unroll
      for (int i = 0; i < 4; ++i) {
        int chunk = i * 256 + tid;
        if (chunk < 512) {
          int row = chunk >> 3;
          int cs = (chunk & 7) ^ (row & 7);
          GLD16(K + hb + (size_t)(kv0 + 64 + row) * 64 + cs * 8, nk + chunk * 16);
        } else {
          int vc = chunk - 512;
          int vrow = vc >> 3;
          int vcs = (vc & 7) ^ (vrow & 7);
          GLD16(Vt + hb + (size_t)vrow * 2048 + kv0 + 64 + vcs * 8, nv + vc * 16);
        }
      }
    }
    const char* cb = sK[it & 1];
    const char* vb = sV[it & 1];

#pragma unroll
    for (int kq = 0; kq < 2; ++kq) {
      // ---- QK^T: st[ii][j], col q = j*16+(lane&15), kv = kq*32+ii*16+quad*4+r
      f32x4 st[2][2] = {};
#pragma unroll
      for (int ksd = 0; ksd < 2; ++ksd) {
        bf16x8 kf[2];
#pragma unroll
        for (int ii = 0; ii < 2; ++ii) {
          int row = kq * 32 + ii * 16 + (lane & 15);
          kf[ii] = *(const bf16x8*)(cb + row * 128 + ((ksd * 4 + quad) ^ (row & 7)) * 16);
        }
#pragma unroll
        for (int ii = 0; ii < 2; ++ii)
#pragma unroll
          for (int j = 0; j < 2; ++j)
            st[ii][j] = mfma16(kf[ii], qf[j][ksd], st[ii][j]);
      }
      // ---- softmax (base-2) + sP write, balanced swizzle s=(ii*4+quad)^(q&6)
#pragma unroll
      for (int ii = 0; ii < 2; ++ii)
#pragma unroll
        for (int j = 0; j < 2; ++j) {
          f32x4 p;
#pragma unroll
          for (int r = 0; r < 4; ++r) {
            p[r] = EXP2(st[ii][j][r]);
            l[j] += p[r];
          }
          bf16x4 pk;
#pragma unroll
          for (int r = 0; r < 4; ++r) pk[r] = (bf16)p[r];
          int q = j * 16 + (lane & 15);
          int s = (ii * 4 + quad) ^ (q & 6);
          *(bf16x4*)(pw + q * 64 + s * 8) = pk;
        }
      bf16x8 pf[2], vf[4];
#pragma unroll
      for (int mt = 0; mt < 2; ++mt) {
        int q = mt * 16 + (lane & 15);
        pf[mt] = *(const bf16x8*)(pw + q * 64 + ((quad ^ ((q >> 1) & 3)) * 16));
      }
#pragma unroll
      for (int nd = 0; nd < 4; ++nd) {
        int row = nd * 16 + (lane & 15);
        vf[nd] = *(const bf16x8*)(vb + row * 128 + (((kq * 4 + quad) ^ (row & 7)) * 16));
      }
#pragma unroll
      for (int mt = 0; mt < 2; ++mt)
#pragma unroll
        for (int nd = 0; nd < 4; ++nd)
          ctxa[mt][nd] = mfma16(pf[mt], vf[nd], ctxa[mt][nd]);
    }
    __syncthreads();
  }

#pragma unroll
  for (int j = 0; j < 2; ++j) {
    l[j] += __shfl_xor(l[j], 16);
    l[j] += __shfl_xor(l[j], 32);
  }
#pragma unroll
  for (int mt = 0; mt < 2; ++mt)
#pragma unroll
    for (int r = 0; r < 4; ++r) {
      float lsh = __shfl(l[mt], quad * 4 + r);
      float rl = __builtin_amdgcn_rcpf(lsh);
      int srow = q0 + wave * 32 + mt * 16 + quad * 4 + r;
#pragma unroll
      for (int nd = 0; nd < 4; ++nd) {
        int col = h * 64 + nd * 16 + (lane & 15);
        ctx[((size_t)(b * 2048 + srow)) * 1024 + col] = (bf16)(ctxa[mt][nd][r] * rl);
      }
    }
}

// ---------------- GEMM2 (R12): 128^2 counted-vmcnt ----------------
__device__ __forceinline__ void gemm2_core(
    const bf16* __restrict__ Ab, const bf16* __restrict__ Bb,
    char sA[2][128 * 64 * 2], char sB[2][128 * 64 * 2],
    int tid, int lane, int quad, int wm, int wn, f32x4 (&acc)[4][4]) {
  stage_mat(Ab, 0, sA[0], tid);
  stage_bhalf(Bb, 0, sB[0], tid, 0);
  stage_bhalf(Bb, 0, sB[0], tid, 1);

  for (int t = 0; t < 16; ++t) {
    const int cur = t & 1;
    const int ktn = (t + 1) * 64;
    const char* ca = sA[cur];
    const char* cb = sB[cur];
    char* na = sA[cur ^ 1];
    char* nb = sB[cur ^ 1];

    WAITV(2);
    barp();
    bf16x8 af[4][2], bfr[2][2];
#pragma unroll
    for (int mt = 0; mt < 4; ++mt)
#pragma unroll
      for (int ks = 0; ks < 2; ++ks) {
        int ra = wm + mt * 16 + (lane & 15);
        af[mt][ks] = *(const bf16x8*)(ca + ra * 128 + ((ks * 4 + quad) ^ (ra & 7)) * 16);
      }
#pragma unroll
    for (int j = 0; j < 2; ++j)
#pragma unroll
      for (int ks = 0; ks < 2; ++ks) {
        int rb = wn + j * 16 + (lane & 15);
        bfr[j][ks] = *(const bf16x8*)(cb + rb * 128 + ((ks * 4 + quad) ^ (rb & 7)) * 16);
      }
    if (t < 15) {
      stage_mat(Ab, ktn, na, tid);
      stage_bhalf(Bb, ktn, nb, tid, 0);
    }
    __builtin_amdgcn_s_setprio(1);
#pragma unroll
    for (int ks = 0; ks < 2; ++ks)
#pragma unroll
      for (int mt = 0; mt < 4; ++mt)
#pragma unroll
        for (int j = 0; j < 2; ++j)
          acc[mt][j] = mfma16(af[mt][ks], bfr[j][ks], acc[mt][j]);
    __builtin_amdgcn_s_setprio(0);

    if (t < 15) {
      WAITV(6);
    } else {
      WAITV(0);
    }
    barp();
#pragma unroll
    for (int j = 0; j < 2; ++j)
#pragma unroll
      for (int ks = 0; ks < 2; ++ks) {
        int rb = wn + (2 + j) * 16 + (lane & 15);
        bfr[j][ks] = *(const bf16x8*)(cb + rb * 128 + ((ks * 4 + quad) ^ (rb & 7)) * 16);
      }
    if (t < 15) stage_bhalf(Bb, ktn, nb, tid, 1);
    __builtin_amdgcn_s_setprio(1);
#pragma unroll
    for (int ks = 0; ks < 2; ++ks)
#pragma unroll
      for (int mt = 0; mt < 4; ++mt)
#pragma unroll
        for (int j = 0; j < 2; ++j)
          acc[mt][2 + j] = mfma16(af[mt][ks], bfr[j][ks], acc[mt][2 + j]);
    __builtin_amdgcn_s_setprio(0);
  }
}

__global__ __launch_bounds__(256, 2) void gemm2_kernel(
    const bf16* __restrict__ A, const bf16* __restrict__ Bt, const float* __restrict__ bias,
    float* __restrict__ Out) {
  __shared__ __align__(16) char sA[2][128 * 64 * 2];
  __shared__ __align__(16) char sB[2][128 * 64 * 2];
  const int tid = threadIdx.x, lane = tid & 63, quad = lane >> 4;
  const int wave = tid >> 6;
  const int id = blockIdx.x, xcd = id & 7, local = id >> 3;
  const int m0 = (xcd * 8 + (local & 7)) * 128, n0 = (local >> 3) * 128;
  const int wm = (wave >> 1) * 64, wn = (wave & 1) * 64;
  f32x4 acc[4][4] = {};

  gemm2_core(A + (size_t)m0 * 1024, Bt + (size_t)n0 * 1024, sA, sB,
             tid, lane, quad, wm, wn, acc);

#pragma unroll
  for (int nt = 0; nt < 4; ++nt) {
    int n = n0 + wn + nt * 16 + (lane & 15);
    float bv = bias[n];
#pragma unroll
    for (int mt = 0; mt < 4; ++mt) {
      int gm = m0 + wm + mt * 16 + quad * 4;
#pragma unroll
      for (int r = 0; r < 4; ++r)
        Out[(size_t)(gm + r) * 1024 + n] = acc[mt][nt][r] + bv;
    }
  }
}

extern "C" void kernel_launch(void* const* d_in, const int* in_sizes, int n_in,
                              void* d_out, int out_size, void* d_ws, size_t ws_size,
                              hipStream_t stream) {
  const float* qkv   = (const float*)d_in[0];
  const float* W_in  = (const float*)d_in[1];
  const float* b_in  = (const float*)d_in[2];
  const float* W_out = (const float*)d_in[3];
  const float* b_out = (const float*)d_in[4];
  float* out = (float*)d_out;

  bf16* Xb    = (bf16*)d_ws;
  bf16* WtIn  = Xb + 8388608;
  bf16* WtOut = WtIn + 3145728;
  bf16* Qb    = WtOut + 1048576;
  bf16* Kb    = Qb + 8388608;
  bf16* Vtb   = Kb + 8388608;
  bf16* Ctx   = Xb;

  prep_kernel<<<12288, 256, 0, stream>>>(qkv, Xb, W_in, WtIn, W_out, WtOut);
  gemm1_kernel<<<512, 512, 0, stream>>>(Xb, WtIn, b_in, Qb, Kb, Vtb);
  flash_kernel<<<1024, 256, 0, stream>>>(Qb, Kb, Vtb, Ctx);
  gemm2_kernel<<<512, 256, 0, stream>>>(Ctx, WtOut, b_out, out);
}

// Round 10
// 250.184 us; speedup vs baseline: 1.0150x; 1.0150x over previous
//
#include <hip/hip_runtime.h>

// Fused MHA: qkv[4,2048,1024] f32 -> out f32, all GEMMs in bf16 MFMA.
// R16: flash REVERTED to v7 (R15 falsified occupancy theory: 2x waves/CU,
// same MfmaUtil, -4% perf). gemm1 reverted to R10 128^2 structure with ONE
// change: coalesced Q/K epilogue. Across R10/R12/R14 (three gemm schedules)
// non-flash time was invariant ~162us; the common element was the Q/K
// scatter epilogue (64 scalar 2B stores/lane, 32B segments). New epilogue:
// per-wave 8KB LDS repack [64s][64d], swizzle byte^=((s>>2)&3)<<5
// (write: 4 quads -> 4 disjoint 32B regions, 2 lanes/bank = free; read:
// 8 lanes/row full-sweep = wire speed), then bf16x8 stores = 1KB fully
// contiguous per wave-store. No barrier (wave-private region, after final
// K-loop barrier). V path unchanged. gemm2 = R12 phased (measured-equal),
// prep unchanged. Pre-commit: total ~245 falsifies store theory -> fuse
// kernels next.

typedef __bf16 bf16;
typedef __bf16 bf16x4 __attribute__((ext_vector_type(4)));
typedef __bf16 bf16x8 __attribute__((ext_vector_type(8)));
typedef float f32x4 __attribute__((ext_vector_type(4)));

typedef const __attribute__((address_space(1))) void* gas1p;
typedef __attribute__((address_space(3))) void* las3p;
#define GLD16(g, l) __builtin_amdgcn_global_load_lds((gas1p)(g), (las3p)(l), 16, 0, 0)

#if __has_builtin(__builtin_amdgcn_exp2f)
#define EXP2(x) __builtin_amdgcn_exp2f(x)
#else
#define EXP2(x) exp2f(x)
#endif

#define WAITV(n) asm volatile("s_waitcnt vmcnt(" #n ")" ::: "memory")

__device__ __forceinline__ void barp() {
  __builtin_amdgcn_sched_barrier(0);
  __builtin_amdgcn_s_barrier();
  __builtin_amdgcn_sched_barrier(0);
}

__device__ __forceinline__ f32x4 mfma16(bf16x8 a, bf16x8 b, f32x4 c) {
  return __builtin_amdgcn_mfma_f32_16x16x32_bf16(a, b, c, 0, 0, 0);
}

// ---------------- prep: cast qkv -> bf16, transpose+cast W_in, W_out ----------------
__global__ void prep_kernel(const float* __restrict__ qkv, bf16* __restrict__ Xb,
                            const float* __restrict__ W_in, bf16* __restrict__ WtIn,
                            const float* __restrict__ W_out, bf16* __restrict__ WtOut) {
  __shared__ float tile[32][33];
  int blk = blockIdx.x, tid = threadIdx.x;
  if (blk < 8192) {
    int i = (blk * 256 + tid) * 4;
    float4 v = *(const float4*)(qkv + i);
    bf16x4 o;
    o[0] = (bf16)v.x; o[1] = (bf16)v.y; o[2] = (bf16)v.z; o[3] = (bf16)v.w;
    *(bf16x4*)(Xb + i) = o;
    return;
  }
  const float* in; bf16* out; int R, C, c0, r0;
  if (blk < 11264) {
    int t = blk - 8192; in = W_in; out = WtIn; R = 1024; C = 3072;
    c0 = (t % 96) * 32; r0 = (t / 96) * 32;
  } else {
    int t = blk - 11264; in = W_out; out = WtOut; R = 1024; C = 1024;
    c0 = (t % 32) * 32; r0 = (t / 32) * 32;
  }
  int tx = tid & 31, ty = tid >> 5;
#pragma unroll
  for (int i = 0; i < 4; ++i)
    tile[ty + i * 8][tx] = in[(size_t)(r0 + ty + i * 8) * C + c0 + tx];
  __syncthreads();
#pragma unroll
  for (int i = 0; i < 4; ++i)
    out[(size_t)(c0 + ty + i * 8) * R + r0 + tx] = (bf16)tile[tx][ty + i * 8];
}

// ======== R10 dbuf-GEMM machinery: 128x128 tile, BK=64, K=1024 ========
__device__ __forceinline__ void stage_tile(const bf16* __restrict__ src, size_t rstride,
                                           int kt, char* dst, int tid) {
#pragma unroll
  for (int i = 0; i < 4; ++i) {
    int chunk = i * 256 + tid;
    int row = chunk >> 3;
    int cs = (chunk & 7) ^ (row & 7);
    GLD16(src + (size_t)row * rstride + kt + cs * 8, dst + chunk * 16);
  }
}

__device__ __forceinline__ void gemm_step(
    const bf16* __restrict__ A, const bf16* __restrict__ B, int m0, int n0,
    const char* ca, const char* cb, char* na, char* nb, int ktn, bool pref,
    int tid, int lane, int quad, int wm, int wn, f32x4 (&acc)[4][4]) {
  if (pref) {
    stage_tile(A + (size_t)m0 * 1024, 1024, ktn, na, tid);
    stage_tile(B + (size_t)n0 * 1024, 1024, ktn, nb, tid);
  }
#pragma unroll
  for (int ks = 0; ks < 2; ++ks) {
    bf16x8 af[4], bfr[4];
#pragma unroll
    for (int t = 0; t < 4; ++t) {
      int ra = wm + t * 16 + (lane & 15);
      af[t] = *(const bf16x8*)(ca + ra * 128 + ((ks * 4 + quad) ^ (ra & 7)) * 16);
      int rb = wn + t * 16 + (lane & 15);
      bfr[t] = *(const bf16x8*)(cb + rb * 128 + ((ks * 4 + quad) ^ (rb & 7)) * 16);
    }
#pragma unroll
    for (int mt = 0; mt < 4; ++mt)
#pragma unroll
      for (int nt = 0; nt < 4; ++nt)
        acc[mt][nt] = mfma16(af[mt], bfr[nt], acc[mt][nt]);
  }
  __syncthreads();
}

// ---------------- GEMM1: R10 structure + coalesced Q/K epilogue ----------------
// 1536 blocks flat. XCD partition: xcd=id&7 owns m-tiles xcd*8..+7.
__global__ __launch_bounds__(256, 2) void gemm1_kernel(
    const bf16* __restrict__ A, const bf16* __restrict__ Bt, const float* __restrict__ bias,
    bf16* __restrict__ Qo, bf16* __restrict__ Ko, bf16* __restrict__ Vo) {
  __shared__ __align__(16) char sA[2][128 * 64 * 2];
  __shared__ __align__(16) char sB[2][128 * 64 * 2];
  const int tid = threadIdx.x, lane = tid & 63, quad = lane >> 4;
  const int wave = tid >> 6;
  const int id = blockIdx.x, xcd = id & 7, local = id >> 3;
  const int m0 = (xcd * 8 + (local & 7)) * 128, n0 = (local >> 3) * 128;
  const int wm = (wave >> 1) * 64, wn = (wave & 1) * 64;
  f32x4 acc[4][4] = {};

  stage_tile(A + (size_t)m0 * 1024, 1024, 0, sA[0], tid);
  stage_tile(Bt + (size_t)n0 * 1024, 1024, 0, sB[0], tid);
  __syncthreads();
  for (int it = 0; it < 16; it += 2) {
    gemm_step(A, Bt, m0, n0, sA[0], sB[0], sA[1], sB[1], (it + 1) * 64, true,
              tid, lane, quad, wm, wn, acc);
    gemm_step(A, Bt, m0, n0, sA[1], sB[1], sA[0], sB[0], (it + 2) * 64, it + 2 < 16,
              tid, lane, quad, wm, wn, acc);
  }
  // final gemm_step ended with __syncthreads: all sA/sB reads complete.

  const int region = n0 >> 10;  // 0=Q, 1=K, 2=V (uniform per block)
  if (region == 2) {
    // V path unchanged: packed bf16x4 along s into Vt[bh][d][s]
#pragma unroll
    for (int nt = 0; nt < 4; ++nt) {
      int n = n0 + wn + nt * 16 + (lane & 15);
      float bv = bias[n];
      int ncol = n & 1023;
      int h = ncol >> 6, d = ncol & 63;
#pragma unroll
      for (int mt = 0; mt < 4; ++mt) {
        int gm = m0 + wm + mt * 16 + quad * 4;
        int bb = gm >> 11, s = gm & 2047;
        bf16x4 pk;
#pragma unroll
        for (int r = 0; r < 4; ++r) pk[r] = (bf16)(acc[mt][nt][r] + bv);
        *(bf16x4*)(Vo + ((size_t)((bb * 16 + h) * 64 + d)) * 2048 + s) = pk;
      }
    }
  } else {
    // Q/K: repack via per-wave LDS [64s][64d] (8KB each, in sA), then
    // fully-coalesced bf16x8 stores (1KB contiguous per wave-store).
    bf16* dst = (region == 0) ? Qo : Ko;
    const float scl = (region == 0) ? 0.18033688f : 1.0f;  // 1/sqrt(64)*log2(e)
    char* rp = sA[0] + wave * 8192;
    const int c = lane & 15;
#pragma unroll
    for (int nt = 0; nt < 4; ++nt) {
      int d_loc = nt * 16 + c;
      float bv = bias[n0 + wn + d_loc];
#pragma unroll
      for (int mt = 0; mt < 4; ++mt) {
#pragma unroll
        for (int r = 0; r < 4; ++r) {
          int s_loc = mt * 16 + quad * 4 + r;
          int byte = s_loc * 128 + ((d_loc * 2) ^ (((s_loc >> 2) & 3) << 5));
          *(bf16*)(rp + byte) = (bf16)((acc[mt][nt][r] + bv) * scl);
        }
      }
    }
    // wave reads only its own region: compiler's lgkmcnt suffices, no barrier.
    const int h = ((n0 + wn) >> 6) & 15;
    const int gmb = m0 + wm;                 // 64-aligned; never crosses 2048
    const int bb = gmb >> 11;
    const size_t outbase = ((size_t)(bb * 16 + h)) * 2048 + (gmb & 2047);
#pragma unroll
    for (int j = 0; j < 8; ++j) {
      int srow = j * 8 + (lane >> 3);
      int chunk = lane & 7;
      int byte = srow * 128 + ((chunk * 16) ^ (((srow >> 2) & 3) << 5));
      bf16x8 v = *(const bf16x8*)(rp + byte);
      *(bf16x8*)(dst + (outbase + srow) * 64 + chunk * 8) = v;
    }
  }
}

// ---------------- flash attention v7: K=32 PV, balanced sP (R10 verbatim) ----------------
__global__ __launch_bounds__(256, 2) void flash_kernel(
    const bf16* __restrict__ Q, const bf16* __restrict__ K, const bf16* __restrict__ Vt,
    bf16* __restrict__ ctx) {
  const int n = blockIdx.x;
  const int bh = (n & 7) * 8 + (n >> 6);   // XCD swizzle: 8 heads share an XCD L2
  const int qt = (n >> 3) & 7;
  const int b = bh >> 4, h = bh & 15;
  const int tid = threadIdx.x, lane = tid & 63, wave = tid >> 6, quad = lane >> 4;

  __shared__ __align__(16) char sK[2][128 * 64 * 2];  // K dbuf, 2x16KB
  __shared__ __align__(16) char sV[2][64 * 128 * 2];  // V dbuf [d][kv], 2x16KB
  __shared__ __align__(16) char sP[4][64 * 32 * 2];   // per-wave [64q][32kv] 4KB

  const size_t hb = (size_t)bh * 2048 * 64;
  const int q0 = qt * 256;

#pragma unroll
  for (int i = 0; i < 8; ++i) {
    int chunk = i * 256 + tid;
    int row = chunk >> 3;
    int cs = (chunk & 7) ^ (row & 7);
    char* dst = (i < 4) ? (sK[0] + chunk * 16) : (sK[1] + (chunk - 1024) * 16);
    GLD16(Q + hb + (size_t)(q0 + row) * 64 + cs * 8, dst);
  }
  __syncthreads();
  bf16x8 qf[4][2];
#pragma unroll
  for (int j = 0; j < 4; ++j)
#pragma unroll
    for (int ksd = 0; ksd < 2; ++ksd) {
      int row = wave * 64 + j * 16 + (lane & 15);
      const char* src = sK[row >> 7];
      int r128 = row & 127;
      qf[j][ksd] = *(const bf16x8*)(src + r128 * 128 + ((ksd * 4 + quad) ^ (r128 & 7)) * 16);
    }
  __syncthreads();

#pragma unroll
  for (int i = 0; i < 4; ++i) {
    int chunk = i * 256 + tid;
    int row = chunk >> 3;
    int cs = (chunk & 7) ^ (row & 7);
    GLD16(K + hb + (size_t)row * 64 + cs * 8, sK[0] + chunk * 16);
    int vrow = chunk >> 4;
    int vcs = (chunk & 15) ^ (vrow & 7);
    GLD16(Vt + hb + (size_t)vrow * 2048 + vcs * 8, sV[0] + chunk * 16);
  }
  __syncthreads();

  f32x4 ctxa[4][4] = {};
  float l[4] = {0.f, 0.f, 0.f, 0.f};
  char* pw = sP[wave];

  for (int it = 0; it < 16; ++it) {
    const int kv0 = it * 128;
    if (it < 15) {
      char* nk = sK[(it + 1) & 1];
      char* nv = sV[(it + 1) & 1];
#pragma unroll
      for (int i = 0; i < 4; ++i) {
        int chunk = i * 256 + tid;
        int row = chunk >> 3;
        int cs = (chunk & 7) ^ (row & 7);
        GLD16(K + hb + (size_t)(kv0 + 128 + row) * 64 + cs * 8, nk + chunk * 16);
        int vrow = chunk >> 4;
        int vcs = (chunk & 15) ^ (vrow & 7);
        GLD16(Vt + hb + (size_t)vrow * 2048 + kv0 + 128 + vcs * 8, nv + chunk * 16);
      }
    }
    const char* cb = sK[it & 1];
    const char* vb = sV[it & 1];

#pragma unroll
    for (int kq = 0; kq < 4; ++kq) {
      f32x4 st[2][4] = {};
#pragma unroll
      for (int ksd = 0; ksd < 2; ++ksd) {
        bf16x8 kf[2];
#pragma unroll
        for (int ii = 0; ii < 2; ++ii) {
          int row = kq * 32 + ii * 16 + (lane & 15);
          kf[ii] = *(const bf16x8*)(cb + row * 128 + ((ksd * 4 + quad) ^ (row & 7)) * 16);
        }
#pragma unroll
        for (int ii = 0; ii < 2; ++ii)
#pragma unroll
          for (int j = 0; j < 4; ++j)
            st[ii][j] = mfma16(kf[ii], qf[j][ksd], st[ii][j]);
      }
#pragma unroll
      for (int ii = 0; ii < 2; ++ii)
#pragma unroll
        for (int j = 0; j < 4; ++j) {
          f32x4 p;
#pragma unroll
          for (int r = 0; r < 4; ++r) {
            p[r] = EXP2(st[ii][j][r]);
            l[j] += p[r];
          }
          bf16x4 pk;
#pragma unroll
          for (int r = 0; r < 4; ++r) pk[r] = (bf16)p[r];
          int q = j * 16 + (lane & 15);
          int s = (ii * 4 + quad) ^ (q & 6);
          *(bf16x4*)(pw + q * 64 + s * 8) = pk;
        }
      bf16x8 pf[4], vf[4];
#pragma unroll
      for (int mt = 0; mt < 4; ++mt) {
        int q = mt * 16 + (lane & 15);
        pf[mt] = *(const bf16x8*)(pw + q * 64 + ((quad ^ ((q >> 1) & 3)) * 16));
      }
#pragma unroll
      for (int nd = 0; nd < 4; ++nd) {
        int row = nd * 16 + (lane & 15);
        vf[nd] = *(const bf16x8*)(vb + row * 256 + (((kq * 4 + quad) ^ (row & 7)) * 16));
      }
#pragma unroll
      for (int mt = 0; mt < 4; ++mt)
#pragma unroll
        for (int nd = 0; nd < 4; ++nd)
          ctxa[mt][nd] = mfma16(pf[mt], vf[nd], ctxa[mt][nd]);
    }
    __syncthreads();
  }

#pragma unroll
  for (int j = 0; j < 4; ++j) {
    l[j] += __shfl_xor(l[j], 16);
    l[j] += __shfl_xor(l[j], 32);
  }
#pragma unroll
  for (int mt = 0; mt < 4; ++mt)
#pragma unroll
    for (int r = 0; r < 4; ++r) {
      float lsh = __shfl(l[mt], quad * 4 + r);
      float rl = __builtin_amdgcn_rcpf(lsh);
      int srow = q0 + wave * 64 + mt * 16 + quad * 4 + r;
#pragma unroll
      for (int nd = 0; nd < 4; ++nd) {
        int col = h * 64 + nd * 16 + (lane & 15);
        ctx[((size_t)(b * 2048 + srow)) * 1024 + col] = (bf16)(ctxa[mt][nd][r] * rl);
      }
    }
}

// ---------------- GEMM2 (R12): 128^2 counted-vmcnt ----------------
__device__ __forceinline__ void stage_mat(const bf16* __restrict__ src, int kt,
                                          char* dst, int tid) {
#pragma unroll
  for (int i = 0; i < 4; ++i) {
    int chunk = i * 256 + tid;
    int row = chunk >> 3;
    int cs = (chunk & 7) ^ (row & 7);
    GLD16(src + (size_t)row * 1024 + kt + cs * 8, dst + chunk * 16);
  }
}
__device__ __forceinline__ void stage_bhalf(const bf16* __restrict__ src, int kt,
                                            char* dst, int tid, int b) {
#pragma unroll
  for (int i = 0; i < 2; ++i) {
    int chunk = (i * 64 + b * 32) * 8 + tid;
    int row = chunk >> 3;
    int cs = (chunk & 7) ^ (row & 7);
    GLD16(src + (size_t)row * 1024 + kt + cs * 8, dst + chunk * 16);
  }
}

__device__ __forceinline__ void gemm2_core(
    const bf16* __restrict__ Ab, const bf16* __restrict__ Bb,
    char sA[2][128 * 64 * 2], char sB[2][128 * 64 * 2],
    int tid, int lane, int quad, int wm, int wn, f32x4 (&acc)[4][4]) {
  stage_mat(Ab, 0, sA[0], tid);
  stage_bhalf(Bb, 0, sB[0], tid, 0);
  stage_bhalf(Bb, 0, sB[0], tid, 1);

  for (int t = 0; t < 16; ++t) {
    const int cur = t & 1;
    const int ktn = (t + 1) * 64;
    const char* ca = sA[cur];
    const char* cb = sB[cur];
    char* na = sA[cur ^ 1];
    char* nb = sB[cur ^ 1];

    WAITV(2);
    barp();
    bf16x8 af[4][2], bfr[2][2];
#pragma unroll
    for (int mt = 0; mt < 4; ++mt)
#pragma unroll
      for (int ks = 0; ks < 2; ++ks) {
        int ra = wm + mt * 16 + (lane & 15);
        af[mt][ks] = *(const bf16x8*)(ca + ra * 128 + ((ks * 4 + quad) ^ (ra & 7)) * 16);
      }
#pragma unroll
    for (int j = 0; j < 2; ++j)
#pragma unroll
      for (int ks = 0; ks < 2; ++ks) {
        int rb = wn + j * 16 + (lane & 15);
        bfr[j][ks] = *(const bf16x8*)(cb + rb * 128 + ((ks * 4 + quad) ^ (rb & 7)) * 16);
      }
    if (t < 15) {
      stage_mat(Ab, ktn, na, tid);
      stage_bhalf(Bb, ktn, nb, tid, 0);
    }
    __builtin_amdgcn_s_setprio(1);
#pragma unroll
    for (int ks = 0; ks < 2; ++ks)
#pragma unroll
      for (int mt = 0; mt < 4; ++mt)
#pragma unroll
        for (int j = 0; j < 2; ++j)
          acc[mt][j] = mfma16(af[mt][ks], bfr[j][ks], acc[mt][j]);
    __builtin_amdgcn_s_setprio(0);

    if (t < 15) {
      WAITV(6);
    } else {
      WAITV(0);
    }
    barp();
#pragma unroll
    for (int j = 0; j < 2; ++j)
#pragma unroll
      for (int ks = 0; ks < 2; ++ks) {
        int rb = wn + (2 + j) * 16 + (lane & 15);
        bfr[j][ks] = *(const bf16x8*)(cb + rb * 128 + ((ks * 4 + quad) ^ (rb & 7)) * 16);
      }
    if (t < 15) stage_bhalf(Bb, ktn, nb, tid, 1);
    __builtin_amdgcn_s_setprio(1);
#pragma unroll
    for (int ks = 0; ks < 2; ++ks)
#pragma unroll
      for (int mt = 0; mt < 4; ++mt)
#pragma unroll
        for (int j = 0; j < 2; ++j)
          acc[mt][2 + j] = mfma16(af[mt][ks], bfr[j][ks], acc[mt][2 + j]);
    __builtin_amdgcn_s_setprio(0);
  }
}

__global__ __launch_bounds__(256, 2) void gemm2_kernel(
    const bf16* __restrict__ A, const bf16* __restrict__ Bt, const float* __restrict__ bias,
    float* __restrict__ Out) {
  __shared__ __align__(16) char sA[2][128 * 64 * 2];
  __shared__ __align__(16) char sB[2][128 * 64 * 2];
  const int tid = threadIdx.x, lane = tid & 63, quad = lane >> 4;
  const int wave = tid >> 6;
  const int id = blockIdx.x, xcd = id & 7, local = id >> 3;
  const int m0 = (xcd * 8 + (local & 7)) * 128, n0 = (local >> 3) * 128;
  const int wm = (wave >> 1) * 64, wn = (wave & 1) * 64;
  f32x4 acc[4][4] = {};

  gemm2_core(A + (size_t)m0 * 1024, Bt + (size_t)n0 * 1024, sA, sB,
             tid, lane, quad, wm, wn, acc);

#pragma unroll
  for (int nt = 0; nt < 4; ++nt) {
    int n = n0 + wn + nt * 16 + (lane & 15);
    float bv = bias[n];
#pragma unroll
    for (int mt = 0; mt < 4; ++mt) {
      int gm = m0 + wm + mt * 16 + quad * 4;
#pragma unroll
      for (int r = 0; r < 4; ++r)
        Out[(size_t)(gm + r) * 1024 + n] = acc[mt][nt][r] + bv;
    }
  }
}

extern "C" void kernel_launch(void* const* d_in, const int* in_sizes, int n_in,
                              void* d_out, int out_size, void* d_ws, size_t ws_size,
                              hipStream_t stream) {
  const float* qkv   = (const float*)d_in[0];
  const float* W_in  = (const float*)d_in[1];
  const float* b_in  = (const float*)d_in[2];
  const float* W_out = (const float*)d_in[3];
  const float* b_out = (const float*)d_in[4];
  float* out = (float*)d_out;

  bf16* Xb    = (bf16*)d_ws;
  bf16* WtIn  = Xb + 8388608;
  bf16* WtOut = WtIn + 3145728;
  bf16* Qb    = WtOut + 1048576;
  bf16* Kb    = Qb + 8388608;
  bf16* Vtb   = Kb + 8388608;
  bf16* Ctx   = Xb;

  prep_kernel<<<12288, 256, 0, stream>>>(qkv, Xb, W_in, WtIn, W_out, WtOut);
  gemm1_kernel<<<1536, 256, 0, stream>>>(Xb, WtIn, b_in, Qb, Kb, Vtb);
  flash_kernel<<<512, 256, 0, stream>>>(Qb, Kb, Vtb, Ctx);
  gemm2_kernel<<<512, 256, 0, stream>>>(Ctx, WtOut, b_out, out);
}

// Round 14
// 237.538 us; speedup vs baseline: 1.0691x; 1.0532x over previous
//
#include <hip/hip_runtime.h>

// Fused MHA: qkv[4,2048,1024] f32 -> out f32, all GEMMs in bf16 MFMA.
// R20 = byte-identical rollback to R12, the best MEASURED config
// (245.03us, passed, Round 6). R18/R19 (R12 + widened prep cast) hit two
// consecutive "container failed twice" infra errors — same source twice;
// rolling back to the measured artifact both banks the best result and
// discriminates kernel-induced vs environment-side failure. The prep
// widening (~1us upside) is abandoned.
// Ledger: win = flash sP balanced swizzle + K=32 PV (R10). Falsified:
// gemm K-schedule (R12-neutral), 256x192 tile economics (R14-neutral),
// flash occupancy (R15-hurt), Q/K store coalescing (R16-neutral),
// P-in-register K=16 PV (R9-hurt), setprio in lockstep flash (R7-hurt).
// R17 cooperative fusion failed correctness (cross-XCD L2 visibility, G16).

typedef __bf16 bf16;
typedef __bf16 bf16x4 __attribute__((ext_vector_type(4)));
typedef __bf16 bf16x8 __attribute__((ext_vector_type(8)));
typedef float f32x4 __attribute__((ext_vector_type(4)));

typedef const __attribute__((address_space(1))) void* gas1p;
typedef __attribute__((address_space(3))) void* las3p;
#define GLD16(g, l) __builtin_amdgcn_global_load_lds((gas1p)(g), (las3p)(l), 16, 0, 0)

#if __has_builtin(__builtin_amdgcn_exp2f)
#define EXP2(x) __builtin_amdgcn_exp2f(x)
#else
#define EXP2(x) exp2f(x)
#endif

// counted vmcnt wait; memory clobber keeps all VMEM/DS ops on their side.
#define WAITV(n) asm volatile("s_waitcnt vmcnt(" #n ")" ::: "memory")

__device__ __forceinline__ void barp() {
  __builtin_amdgcn_sched_barrier(0);
  __builtin_amdgcn_s_barrier();
  __builtin_amdgcn_sched_barrier(0);
}

__device__ __forceinline__ f32x4 mfma16(bf16x8 a, bf16x8 b, f32x4 c) {
  return __builtin_amdgcn_mfma_f32_16x16x32_bf16(a, b, c, 0, 0, 0);
}

// ---------------- prep: cast qkv -> bf16, transpose+cast W_in, W_out ----------------
__global__ void prep_kernel(const float* __restrict__ qkv, bf16* __restrict__ Xb,
                            const float* __restrict__ W_in, bf16* __restrict__ WtIn,
                            const float* __restrict__ W_out, bf16* __restrict__ WtOut) {
  __shared__ float tile[32][33];
  int blk = blockIdx.x, tid = threadIdx.x;
  if (blk < 8192) {
    int i = (blk * 256 + tid) * 4;
    float4 v = *(const float4*)(qkv + i);
    bf16x4 o;
    o[0] = (bf16)v.x; o[1] = (bf16)v.y; o[2] = (bf16)v.z; o[3] = (bf16)v.w;
    *(bf16x4*)(Xb + i) = o;
    return;
  }
  const float* in; bf16* out; int R, C, c0, r0;
  if (blk < 11264) {
    int t = blk - 8192; in = W_in; out = WtIn; R = 1024; C = 3072;
    c0 = (t % 96) * 32; r0 = (t / 96) * 32;
  } else {
    int t = blk - 11264; in = W_out; out = WtOut; R = 1024; C = 1024;
    c0 = (t % 32) * 32; r0 = (t / 32) * 32;
  }
  int tx = tid & 31, ty = tid >> 5;
#pragma unroll
  for (int i = 0; i < 4; ++i)
    tile[ty + i * 8][tx] = in[(size_t)(r0 + ty + i * 8) * C + c0 + tx];
  __syncthreads();
#pragma unroll
  for (int i = 0; i < 4; ++i)
    out[(size_t)(c0 + ty + i * 8) * R + r0 + tx] = (bf16)tile[tx][ty + i * 8];
}

// ======== phased-GEMM machinery: 128x128 tile, BK=64, K=1024 ========
// Stage one full matrix tile (128 rows x 64 k) = 4 GLD16/thread, lane-linear.
__device__ __forceinline__ void stage_mat(const bf16* __restrict__ src, int kt,
                                          char* dst, int tid) {
#pragma unroll
  for (int i = 0; i < 4; ++i) {
    int chunk = i * 256 + tid;
    int row = chunk >> 3;
    int cs = (chunk & 7) ^ (row & 7);
    GLD16(src + (size_t)row * 1024 + kt + cs * 8, dst + chunk * 16);
  }
}

// Stage B nt-half b: rows [32b,32b+32) U [64+32b,96+32b) = 2 GLD16/thread,
// each region chunk = const + tid (lane-linear, m104-safe).
__device__ __forceinline__ void stage_bhalf(const bf16* __restrict__ src, int kt,
                                            char* dst, int tid, int b) {
#pragma unroll
  for (int i = 0; i < 2; ++i) {
    int chunk = (i * 64 + b * 32) * 8 + tid;
    int row = chunk >> 3;
    int cs = (chunk & 7) ^ (row & 7);
    GLD16(src + (size_t)row * 1024 + kt + cs * 8, dst + chunk * 16);
  }
}

// Shared phased K-loop. acc[mt][nt] as before.
__device__ __forceinline__ void gemm_core(
    const bf16* __restrict__ Ab, const bf16* __restrict__ Bb,
    char sA[2][128 * 64 * 2], char sB[2][128 * 64 * 2],
    int tid, int lane, int quad, int wm, int wn, f32x4 (&acc)[4][4]) {
  // prologue: tile 0 units in FIFO order A, B0, B1 (8 loads outstanding)
  stage_mat(Ab, 0, sA[0], tid);
  stage_bhalf(Bb, 0, sB[0], tid, 0);
  stage_bhalf(Bb, 0, sB[0], tid, 1);

  for (int t = 0; t < 16; ++t) {
    const int cur = t & 1;
    const int ktn = (t + 1) * 64;
    const char* ca = sA[cur];
    const char* cb = sB[cur];
    char* na = sA[cur ^ 1];
    char* nb = sB[cur ^ 1];

    // ---------- phase 0: needs A(t), B0(t); B1(t) may stay in flight ----
    WAITV(2);
    barp();
    bf16x8 af[4][2], bfr[2][2];
#pragma unroll
    for (int mt = 0; mt < 4; ++mt)
#pragma unroll
      for (int ks = 0; ks < 2; ++ks) {
        int ra = wm + mt * 16 + (lane & 15);
        af[mt][ks] = *(const bf16x8*)(ca + ra * 128 + ((ks * 4 + quad) ^ (ra & 7)) * 16);
      }
#pragma unroll
    for (int j = 0; j < 2; ++j)
#pragma unroll
      for (int ks = 0; ks < 2; ++ks) {
        int rb = wn + j * 16 + (lane & 15);
        bfr[j][ks] = *(const bf16x8*)(cb + rb * 128 + ((ks * 4 + quad) ^ (rb & 7)) * 16);
      }
    if (t < 15) {
      stage_mat(Ab, ktn, na, tid);        // A(t+1): 4 loads
      stage_bhalf(Bb, ktn, nb, tid, 0);   // B0(t+1): 2 loads
    }
    __builtin_amdgcn_s_setprio(1);
#pragma unroll
    for (int ks = 0; ks < 2; ++ks)
#pragma unroll
      for (int mt = 0; mt < 4; ++mt)
#pragma unroll
        for (int j = 0; j < 2; ++j)
          acc[mt][j] = mfma16(af[mt][ks], bfr[j][ks], acc[mt][j]);
    __builtin_amdgcn_s_setprio(0);

    // ---------- phase 1: needs B1(t); A(t+1),B0(t+1) stay in flight -----
    if (t < 15) {
      WAITV(6);
    } else {
      WAITV(0);
    }
    barp();
#pragma unroll
    for (int j = 0; j < 2; ++j)
#pragma unroll
      for (int ks = 0; ks < 2; ++ks) {
        int rb = wn + (2 + j) * 16 + (lane & 15);
        bfr[j][ks] = *(const bf16x8*)(cb + rb * 128 + ((ks * 4 + quad) ^ (rb & 7)) * 16);
      }
    if (t < 15) stage_bhalf(Bb, ktn, nb, tid, 1);  // B1(t+1): 2 loads
    __builtin_amdgcn_s_setprio(1);
#pragma unroll
    for (int ks = 0; ks < 2; ++ks)
#pragma unroll
      for (int mt = 0; mt < 4; ++mt)
#pragma unroll
        for (int j = 0; j < 2; ++j)
          acc[mt][2 + j] = mfma16(af[mt][ks], bfr[j][ks], acc[mt][2 + j]);
    __builtin_amdgcn_s_setprio(0);
  }
}

// ---------------- GEMM1: A[8192,1024] @ Bt[3072,1024]^T + bias -> Q,K,Vt (bf16) ----------------
__global__ __launch_bounds__(256, 2) void gemm1_kernel(
    const bf16* __restrict__ A, const bf16* __restrict__ Bt, const float* __restrict__ bias,
    bf16* __restrict__ Qo, bf16* __restrict__ Ko, bf16* __restrict__ Vo) {
  __shared__ __align__(16) char sA[2][128 * 64 * 2];
  __shared__ __align__(16) char sB[2][128 * 64 * 2];
  const int tid = threadIdx.x, lane = tid & 63, quad = lane >> 4;
  const int wave = tid >> 6;
  const int id = blockIdx.x, xcd = id & 7, local = id >> 3;
  const int m0 = (xcd * 8 + (local & 7)) * 128, n0 = (local >> 3) * 128;
  const int wm = (wave >> 1) * 64, wn = (wave & 1) * 64;
  f32x4 acc[4][4] = {};

  gemm_core(A + (size_t)m0 * 1024, Bt + (size_t)n0 * 1024, sA, sB,
            tid, lane, quad, wm, wn, acc);

  const int region = n0 >> 10;  // 0=Q, 1=K, 2=V
#pragma unroll
  for (int nt = 0; nt < 4; ++nt) {
    int n = n0 + wn + nt * 16 + (lane & 15);
    float bv = bias[n];
    int ncol = n & 1023;
    int h = ncol >> 6, d = ncol & 63;
#pragma unroll
    for (int mt = 0; mt < 4; ++mt) {
      int gm = m0 + wm + mt * 16 + quad * 4;
      int bb = gm >> 11, s = gm & 2047;
      if (region == 2) {
        bf16x4 pk;
#pragma unroll
        for (int r = 0; r < 4; ++r) pk[r] = (bf16)(acc[mt][nt][r] + bv);
        *(bf16x4*)(Vo + ((size_t)((bb * 16 + h) * 64 + d)) * 2048 + s) = pk;
      } else {
        bf16* dst = (region == 0) ? Qo : Ko;
        // Q scale: 1/sqrt(64) * log2(e)  (softmax done in base-2)
        float scl = (region == 0) ? 0.18033688f : 1.0f;
#pragma unroll
        for (int r = 0; r < 4; ++r)
          dst[((size_t)((bb * 16 + h) * 2048) + s + r) * 64 + d] =
              (bf16)((acc[mt][nt][r] + bv) * scl);
      }
    }
  }
}

// ---------------- flash attention v7: K=32 PV, balanced sP (unchanged) ----------------
__global__ __launch_bounds__(256, 2) void flash_kernel(
    const bf16* __restrict__ Q, const bf16* __restrict__ K, const bf16* __restrict__ Vt,
    bf16* __restrict__ ctx) {
  const int n = blockIdx.x;
  const int bh = (n & 7) * 8 + (n >> 6);   // XCD swizzle: 8 heads share an XCD L2
  const int qt = (n >> 3) & 7;
  const int b = bh >> 4, h = bh & 15;
  const int tid = threadIdx.x, lane = tid & 63, wave = tid >> 6, quad = lane >> 4;

  __shared__ __align__(16) char sK[2][128 * 64 * 2];  // K dbuf, 2x16KB
  __shared__ __align__(16) char sV[2][64 * 128 * 2];  // V dbuf [d][kv], 2x16KB
  __shared__ __align__(16) char sP[4][64 * 32 * 2];   // per-wave [64q][32kv] 4KB

  const size_t hb = (size_t)bh * 2048 * 64;
  const int q0 = qt * 256;

#pragma unroll
  for (int i = 0; i < 8; ++i) {
    int chunk = i * 256 + tid;
    int row = chunk >> 3;
    int cs = (chunk & 7) ^ (row & 7);
    char* dst = (i < 4) ? (sK[0] + chunk * 16) : (sK[1] + (chunk - 1024) * 16);
    GLD16(Q + hb + (size_t)(q0 + row) * 64 + cs * 8, dst);
  }
  __syncthreads();
  bf16x8 qf[4][2];
#pragma unroll
  for (int j = 0; j < 4; ++j)
#pragma unroll
    for (int ksd = 0; ksd < 2; ++ksd) {
      int row = wave * 64 + j * 16 + (lane & 15);
      const char* src = sK[row >> 7];
      int r128 = row & 127;
      qf[j][ksd] = *(const bf16x8*)(src + r128 * 128 + ((ksd * 4 + quad) ^ (r128 & 7)) * 16);
    }
  __syncthreads();

#pragma unroll
  for (int i = 0; i < 4; ++i) {
    int chunk = i * 256 + tid;
    int row = chunk >> 3;
    int cs = (chunk & 7) ^ (row & 7);
    GLD16(K + hb + (size_t)row * 64 + cs * 8, sK[0] + chunk * 16);
    int vrow = chunk >> 4;
    int vcs = (chunk & 15) ^ (vrow & 7);
    GLD16(Vt + hb + (size_t)vrow * 2048 + vcs * 8, sV[0] + chunk * 16);
  }
  __syncthreads();

  f32x4 ctxa[4][4] = {};
  float l[4] = {0.f, 0.f, 0.f, 0.f};
  char* pw = sP[wave];

  for (int it = 0; it < 16; ++it) {
    const int kv0 = it * 128;
    if (it < 15) {
      char* nk = sK[(it + 1) & 1];
      char* nv = sV[(it + 1) & 1];
#pragma unroll
      for (int i = 0; i < 4; ++i) {
        int chunk = i * 256 + tid;
        int row = chunk >> 3;
        int cs = (chunk & 7) ^ (row & 7);
        GLD16(K + hb + (size_t)(kv0 + 128 + row) * 64 + cs * 8, nk + chunk * 16);
        int vrow = chunk >> 4;
        int vcs = (chunk & 15) ^ (vrow & 7);
        GLD16(Vt + hb + (size_t)vrow * 2048 + kv0 + 128 + vcs * 8, nv + chunk * 16);
      }
    }
    const char* cb = sK[it & 1];
    const char* vb = sV[it & 1];

#pragma unroll
    for (int kq = 0; kq < 4; ++kq) {
      // ---- QK^T: st[ii][j], col q = j*16+(lane&15), row kv = kq*32+ii*16+quad*4+r
      f32x4 st[2][4] = {};
#pragma unroll
      for (int ksd = 0; ksd < 2; ++ksd) {
        bf16x8 kf[2];
#pragma unroll
        for (int ii = 0; ii < 2; ++ii) {
          int row = kq * 32 + ii * 16 + (lane & 15);
          kf[ii] = *(const bf16x8*)(cb + row * 128 + ((ksd * 4 + quad) ^ (row & 7)) * 16);
        }
#pragma unroll
        for (int ii = 0; ii < 2; ++ii)
#pragma unroll
          for (int j = 0; j < 4; ++j)
            st[ii][j] = mfma16(kf[ii], qf[j][ksd], st[ii][j]);
      }
      // ---- softmax (base-2) + sP write, balanced swizzle s=(ii*4+quad)^(q&6)
#pragma unroll
      for (int ii = 0; ii < 2; ++ii)
#pragma unroll
        for (int j = 0; j < 4; ++j) {
          f32x4 p;
#pragma unroll
          for (int r = 0; r < 4; ++r) {
            p[r] = EXP2(st[ii][j][r]);
            l[j] += p[r];
          }
          bf16x4 pk;
#pragma unroll
          for (int r = 0; r < 4; ++r) pk[r] = (bf16)p[r];
          int q = j * 16 + (lane & 15);
          int s = (ii * 4 + quad) ^ (q & 6);
          *(bf16x4*)(pw + q * 64 + s * 8) = pk;
        }
      bf16x8 pf[4], vf[4];
#pragma unroll
      for (int mt = 0; mt < 4; ++mt) {
        int q = mt * 16 + (lane & 15);
        pf[mt] = *(const bf16x8*)(pw + q * 64 + ((quad ^ ((q >> 1) & 3)) * 16));
      }
#pragma unroll
      for (int nd = 0; nd < 4; ++nd) {
        int row = nd * 16 + (lane & 15);
        vf[nd] = *(const bf16x8*)(vb + row * 256 + (((kq * 4 + quad) ^ (row & 7)) * 16));
      }
#pragma unroll
      for (int mt = 0; mt < 4; ++mt)
#pragma unroll
        for (int nd = 0; nd < 4; ++nd)
          ctxa[mt][nd] = mfma16(pf[mt], vf[nd], ctxa[mt][nd]);
    }
    __syncthreads();
  }

#pragma unroll
  for (int j = 0; j < 4; ++j) {
    l[j] += __shfl_xor(l[j], 16);
    l[j] += __shfl_xor(l[j], 32);
  }
#pragma unroll
  for (int mt = 0; mt < 4; ++mt)
#pragma unroll
    for (int r = 0; r < 4; ++r) {
      float lsh = __shfl(l[mt], quad * 4 + r);
      float rl = __builtin_amdgcn_rcpf(lsh);
      int srow = q0 + wave * 64 + mt * 16 + quad * 4 + r;
#pragma unroll
      for (int nd = 0; nd < 4; ++nd) {
        int col = h * 64 + nd * 16 + (lane & 15);
        ctx[((size_t)(b * 2048 + srow)) * 1024 + col] = (bf16)(ctxa[mt][nd][r] * rl);
      }
    }
}

// ---------------- GEMM2: ctx[8192,1024] @ Bt[1024,1024]^T + b_out -> f32 out ----------------
__global__ __launch_bounds__(256, 2) void gemm2_kernel(
    const bf16* __restrict__ A, const bf16* __restrict__ Bt, const float* __restrict__ bias,
    float* __restrict__ Out) {
  __shared__ __align__(16) char sA[2][128 * 64 * 2];
  __shared__ __align__(16) char sB[2][128 * 64 * 2];
  const int tid = threadIdx.x, lane = tid & 63, quad = lane >> 4;
  const int wave = tid >> 6;
  const int id = blockIdx.x, xcd = id & 7, local = id >> 3;
  const int m0 = (xcd * 8 + (local & 7)) * 128, n0 = (local >> 3) * 128;
  const int wm = (wave >> 1) * 64, wn = (wave & 1) * 64;
  f32x4 acc[4][4] = {};

  gemm_core(A + (size_t)m0 * 1024, Bt + (size_t)n0 * 1024, sA, sB,
            tid, lane, quad, wm, wn, acc);

#pragma unroll
  for (int nt = 0; nt < 4; ++nt) {
    int n = n0 + wn + nt * 16 + (lane & 15);
    float bv = bias[n];
#pragma unroll
    for (int mt = 0; mt < 4; ++mt) {
      int gm = m0 + wm + mt * 16 + quad * 4;
#pragma unroll
      for (int r = 0; r < 4; ++r)
        Out[(size_t)(gm + r) * 1024 + n] = acc[mt][nt][r] + bv;
    }
  }
}

extern "C" void kernel_launch(void* const* d_in, const int* in_sizes, int n_in,
                              void* d_out, int out_size, void* d_ws, size_t ws_size,
                              hipStream_t stream) {
  const float* qkv   = (const float*)d_in[0];
  const float* W_in  = (const float*)d_in[1];
  const float* b_in  = (const float*)d_in[2];
  const float* W_out = (const float*)d_in[3];
  const float* b_out = (const float*)d_in[4];
  float* out = (float*)d_out;

  bf16* Xb    = (bf16*)d_ws;
  bf16* WtIn  = Xb + 8388608;
  bf16* WtOut = WtIn + 3145728;
  bf16* Qb    = WtOut + 1048576;
  bf16* Kb    = Qb + 8388608;
  bf16* Vtb   = Kb + 8388608;
  bf16* Ctx   = Xb;

  prep_kernel<<<12288, 256, 0, stream>>>(qkv, Xb, W_in, WtIn, W_out, WtOut);
  gemm1_kernel<<<1536, 256, 0, stream>>>(Xb, WtIn, b_in, Qb, Kb, Vtb);
  flash_kernel<<<512, 256, 0, stream>>>(Qb, Kb, Vtb, Ctx);
  gemm2_kernel<<<512, 256, 0, stream>>>(Ctx, WtOut, b_out, out);
}